// Round 11
// baseline (222.664 us; speedup 1.0000x reference)
//
#include <hip/hip_runtime.h>
#include <hip/hip_bf16.h>

#define SN 2048      // sequence length
#define HD 256       // hidden
#define NHEAD 8
#define DK 32
#define BH 16

typedef __bf16 bf16;
typedef __bf16 bf16x8 __attribute__((ext_vector_type(8)));
typedef __bf16 bf16x4 __attribute__((ext_vector_type(4)));
typedef float f32x4 __attribute__((ext_vector_type(4)));
typedef int i32x4 __attribute__((ext_vector_type(4)));
typedef unsigned uint4v __attribute__((ext_vector_type(4)));

// ---------------------------------------------------------------------------
// Kernel 1: transpose Wq/Wk/Wv/Wo (fp32 -> bf16, [k][n] -> [n][k]).
// ---------------------------------------------------------------------------
__global__ void __launch_bounds__(256) prep_wt_kernel(
    const float* __restrict__ Wq, const float* __restrict__ Wk,
    const float* __restrict__ Wv, const float* __restrict__ Wo,
    bf16* __restrict__ wt)
{
    __shared__ bf16 tile[32][HD + 8];
    int mat = blockIdx.x >> 3, rc = blockIdx.x & 7;
    int t = threadIdx.x;
    const float* W = mat == 0 ? Wq : mat == 1 ? Wk : mat == 2 ? Wv : Wo;
    bf16* Wt = wt + mat * HD * HD;
    int r0 = rc * 32;
    #pragma unroll
    for (int i = 0; i < 32; i++) tile[i][t] = (bf16)W[(r0 + i) * HD + t];
    __syncthreads();
    #pragma unroll
    for (int i = 0; i < 32; i++) Wt[t * HD + r0 + i] = tile[i][t];
}

// ---------------------------------------------------------------------------
// 2048x256 @ 256x256 GEMM (MFMA 16x16x32 bf16), Wt [n][k], 2-deep register
// rotation. AF32: fp32 A. MODE 0: out[m][n]; MODE 1: out[n][m]. OUTF32: fp32.
// ---------------------------------------------------------------------------
template<bool AF32, int MODE, bool OUTF32>
__device__ __forceinline__ void gemm_body(
    const void* __restrict__ Ap, const bf16* __restrict__ Wt,
    const float* __restrict__ bias, void* __restrict__ outp, int bid)
{
    int wave = threadIdx.x >> 6, lane = threadIdx.x & 63;
    int g = lane >> 4, qi = lane & 15;
    int mblk = bid & 31, nblk = bid >> 5;
    int m0 = mblk * 64 + wave * 16, n0 = nblk * 32;
    f32x4 acc0 = {0.f, 0.f, 0.f, 0.f}, acc1 = {0.f, 0.f, 0.f, 0.f};
    const bf16* W0 = Wt + (n0 + qi) * HD + 8 * g;
    const bf16* W1 = W0 + 16 * HD;

    auto loadA = [&](int ks) -> bf16x8 {
        if constexpr (AF32) {
            const float* Ar = (const float*)Ap + (m0 + qi) * HD + 8 * g + ks * 32;
            f32x4 lo = *(const f32x4*)Ar;
            f32x4 hi = *(const f32x4*)(Ar + 4);
            bf16x8 a;
            #pragma unroll
            for (int e = 0; e < 4; e++) { a[e] = (bf16)lo[e]; a[4 + e] = (bf16)hi[e]; }
            return a;
        } else {
            return *(const bf16x8*)((const bf16*)Ap + (m0 + qi) * HD + 8 * g + ks * 32);
        }
    };

    bf16x8 a_c  = loadA(0);
    bf16x8 b0_c = *(const bf16x8*)(W0);
    bf16x8 b1_c = *(const bf16x8*)(W1);
    #pragma unroll
    for (int ks = 0; ks < 8; ks++) {
        bf16x8 a_n, b0_n, b1_n;
        if (ks < 7) {
            a_n  = loadA(ks + 1);
            b0_n = *(const bf16x8*)(W0 + (ks + 1) * 32);
            b1_n = *(const bf16x8*)(W1 + (ks + 1) * 32);
        }
        acc0 = __builtin_amdgcn_mfma_f32_16x16x32_bf16(a_c, b0_c, acc0, 0, 0, 0);
        acc1 = __builtin_amdgcn_mfma_f32_16x16x32_bf16(a_c, b1_c, acc1, 0, 0, 0);
        if (ks < 7) { a_c = a_n; b0_c = b0_n; b1_c = b1_n; }
    }
    float bv0 = bias[n0 + qi], bv1 = bias[n0 + 16 + qi];
    if constexpr (MODE == 0) {
        if constexpr (OUTF32) {
            float* out = (float*)outp;
            #pragma unroll
            for (int r = 0; r < 4; r++) {
                int m = m0 + 4 * g + r;
                out[m * HD + n0 + qi]      = acc0[r] + bv0;
                out[m * HD + n0 + 16 + qi] = acc1[r] + bv1;
            }
        } else {
            bf16* out = (bf16*)outp;
            #pragma unroll
            for (int r = 0; r < 4; r++) {
                int m = m0 + 4 * g + r;
                out[m * HD + n0 + qi]      = (bf16)(acc0[r] + bv0);
                out[m * HD + n0 + 16 + qi] = (bf16)(acc1[r] + bv1);
            }
        }
    } else {
        bf16* out = (bf16*)outp;
        bf16x4 v0, v1;
        #pragma unroll
        for (int r = 0; r < 4; r++) { v0[r] = (bf16)(acc0[r] + bv0); v1[r] = (bf16)(acc1[r] + bv1); }
        *(bf16x4*)(out + (n0 + qi) * SN + m0 + 4 * g)      = v0;
        *(bf16x4*)(out + (n0 + 16 + qi) * SN + m0 + 4 * g) = v1;
    }
}

__global__ void __launch_bounds__(256) qkv_kernel(
    const float* __restrict__ q, const float* __restrict__ k, const float* __restrict__ v,
    const bf16* __restrict__ wt,
    const float* __restrict__ bq, const float* __restrict__ bk, const float* __restrict__ bv,
    bf16* __restrict__ qh, bf16* __restrict__ kh, bf16* __restrict__ vt)
{
    int w = blockIdx.y;
    if (w == 0)      gemm_body<true, 0, false>(q, wt,               bq, qh, blockIdx.x);
    else if (w == 1) gemm_body<true, 0, false>(k, wt + HD * HD,     bk, kh, blockIdx.x);
    else             gemm_body<true, 1, false>(v, wt + 2 * HD * HD, bv, vt, blockIdx.x);
}

__global__ void __launch_bounds__(256) oproj_kernel(
    const bf16* __restrict__ A, const bf16* __restrict__ wt3,
    const float* __restrict__ bo, float* __restrict__ out)
{
    gemm_body<false, 0, true>(A, wt3, bo, out, blockIdx.x);
}

// ---------------------------------------------------------------------------
// Kernel 3: MFMA flash attention, split-K (template KCHT), FENCE-FREE:
// the P re-fragmentation is done with __shfl (ds_bpermute) instead of an LDS
// bounce. R10 lesson: the asm ::: "memory" fences around the LDS exchange
// blocked ALL cross-iteration memory reordering (that was the serialization);
// shfl ordering is carried by SSA dataflow, so the compiler can pipeline
// tiles on its own. No LDS at all; VGPR stays ~R9 level.
//
// Exchange math (lane (g,qi) holds x[4s+r] = P(key0+16s+4g+r, q=qi)):
//   pb0 word w (keys 8g+2w,8g+2w+1):  src lane = ((g&1)*2 + (w>>1))*16 + qi,
//   value = pack pair (w&1) of score-block s = (lane>=32), i.e. c[2s+(w&1)].
//   pb1 identical with s += 2.
// All shfls executed unconditionally (full exec); select AFTER the shfl.
// ---------------------------------------------------------------------------
template<int KCHT>
__global__ void __launch_bounds__(128) attn_kernel(
    const bf16* __restrict__ qh, const bf16* __restrict__ kh,
    const bf16* __restrict__ vt,
    const int* __restrict__ label, const float* __restrict__ dist,
    const float* __restrict__ contact,
    const float* __restrict__ Wd1, const float* __restrict__ bd1,
    const float* __restrict__ Wd2, const float* __restrict__ bd2,
    const float* __restrict__ Wc1, const float* __restrict__ bc1,
    const float* __restrict__ Wc2, const float* __restrict__ bc2,
    float* __restrict__ po, float* __restrict__ pm, float* __restrict__ pl)
{
    constexpr int KT = SN / KCHT / 64;   // 64-key tiles per chunk
    int wave = threadIdx.x >> 6, lane = threadIdx.x & 63;
    int g = lane >> 4, qi = lane & 15;
    int h = blockIdx.x / (64 * KCHT);
    int rem = blockIdx.x % (64 * KCHT);
    int qb = rem / KCHT, c = rem % KCHT;
    int q0 = qb * 32 + wave * 16;
    int kbase = c * (KT * 64);

    // fold the two affine pair-MLPs into 4 scalars (wave-uniform, fp32)
    float ad = 0.f, bld = 0.f, dd = bd2[0];
    #pragma unroll
    for (int j = 0; j < BH; j++) {
        float w2 = Wd2[j];
        ad  += Wd1[j] * w2;
        bld += Wd1[BH + j] * w2;
        dd  += bd1[j] * w2;
    }
    float ac = 0.f, blc = 0.f, dc = bc2[0];
    #pragma unroll
    for (int j = 0; j < BH; j++) {
        float w2 = Wc2[j];
        ac  += Wc1[j] * w2;
        blc += Wc1[BH + j] * w2;
        dc  += bc1[j] * w2;
    }
    float bl = bld + blc, dl = dd + dc;

    bf16x8 qf = *(const bf16x8*)(qh + (q0 + qi) * HD + h * DK + 8 * g);
    const bf16* kp  = kh + h * DK + 8 * g + kbase * HD;
    const bf16* v0p = vt + (h * DK + qi) * SN + 8 * g + kbase;
    const bf16* v1p = v0p + 16 * SN;
    const float* dp = dist    + (q0 + qi) * SN + 4 * g + kbase;
    const float* cp = contact + (q0 + qi) * SN + 4 * g + kbase;
    const int*   lp = label   + (q0 + qi) * SN + 4 * g + kbase;

    const float scale = 0.17677669529663687f;  // 32^-0.5
    float m = -1e30f, lsum = 0.f;
    f32x4 o0 = {0.f, 0.f, 0.f, 0.f}, o1 = {0.f, 0.f, 0.f, 0.f};

    int src0 = ((lane >> 4) & 1) * 32 + (lane & 15);
    int src1 = src0 + 16;
    bool hi = lane >= 32;

    #pragma unroll
    for (int kt = 0; kt < KT; kt++) {
        int key0 = kt * 64;
        bf16x8 kf0 = *(const bf16x8*)(kp + (key0 +  0 + qi) * HD);
        bf16x8 kf1 = *(const bf16x8*)(kp + (key0 + 16 + qi) * HD);
        bf16x8 kf2 = *(const bf16x8*)(kp + (key0 + 32 + qi) * HD);
        bf16x8 kf3 = *(const bf16x8*)(kp + (key0 + 48 + qi) * HD);
        f32x4 dv0 = *(const f32x4*)(dp + key0 +  0), dv1 = *(const f32x4*)(dp + key0 + 16);
        f32x4 dv2 = *(const f32x4*)(dp + key0 + 32), dv3 = *(const f32x4*)(dp + key0 + 48);
        f32x4 cv0 = *(const f32x4*)(cp + key0 +  0), cv1 = *(const f32x4*)(cp + key0 + 16);
        f32x4 cv2 = *(const f32x4*)(cp + key0 + 32), cv3 = *(const f32x4*)(cp + key0 + 48);
        i32x4 lv0 = *(const i32x4*)(lp + key0 +  0), lv1 = *(const i32x4*)(lp + key0 + 16);
        i32x4 lv2 = *(const i32x4*)(lp + key0 + 32), lv3 = *(const i32x4*)(lp + key0 + 48);
        bf16x8 va00 = *(const bf16x8*)(v0p + key0);
        bf16x8 va01 = *(const bf16x8*)(v0p + key0 + 32);
        bf16x8 va10 = *(const bf16x8*)(v1p + key0);
        bf16x8 va11 = *(const bf16x8*)(v1p + key0 + 32);

        f32x4 zero = {0.f, 0.f, 0.f, 0.f};
        f32x4 s0 = __builtin_amdgcn_mfma_f32_16x16x32_bf16(kf0, qf, zero, 0, 0, 0);
        f32x4 s1 = __builtin_amdgcn_mfma_f32_16x16x32_bf16(kf1, qf, zero, 0, 0, 0);
        f32x4 s2 = __builtin_amdgcn_mfma_f32_16x16x32_bf16(kf2, qf, zero, 0, 0, 0);
        f32x4 s3 = __builtin_amdgcn_mfma_f32_16x16x32_bf16(kf3, qf, zero, 0, 0, 0);
        float x[16];
        #pragma unroll
        for (int r = 0; r < 4; r++) {
            float b0 = ad * dv0[r] + ac * cv0[r] + bl * (float)lv0[r] + dl;
            float b1 = ad * dv1[r] + ac * cv1[r] + bl * (float)lv1[r] + dl;
            float b2 = ad * dv2[r] + ac * cv2[r] + bl * (float)lv2[r] + dl;
            float b3 = ad * dv3[r] + ac * cv3[r] + bl * (float)lv3[r] + dl;
            x[r]      = s0[r] * scale + b0;
            x[4 + r]  = s1[r] * scale + b1;
            x[8 + r]  = s2[r] * scale + b2;
            x[12 + r] = s3[r] * scale + b3;
        }
        float t0 = fmaxf(x[0], x[1]),   t1 = fmaxf(x[2], x[3]);
        float t2 = fmaxf(x[4], x[5]),   t3 = fmaxf(x[6], x[7]);
        float t4 = fmaxf(x[8], x[9]),   t5 = fmaxf(x[10], x[11]);
        float t6 = fmaxf(x[12], x[13]), t7 = fmaxf(x[14], x[15]);
        float tm = fmaxf(fmaxf(fmaxf(t0, t1), fmaxf(t2, t3)),
                         fmaxf(fmaxf(t4, t5), fmaxf(t6, t7)));
        tm = fmaxf(tm, __shfl_xor(tm, 16));
        tm = fmaxf(tm, __shfl_xor(tm, 32));
        float mnew = fmaxf(m, tm);
        float f = __expf(m - mnew);
        float ps = 0.f;
        #pragma unroll
        for (int i = 0; i < 16; i++) { x[i] = __expf(x[i] - mnew); ps += x[i]; }
        ps += __shfl_xor(ps, 16);
        ps += __shfl_xor(ps, 32);
        lsum = lsum * f + ps;
        m = mnew;
        #pragma unroll
        for (int r = 0; r < 4; r++) { o0[r] *= f; o1[r] *= f; }

        // pack P to bf16 pairs (key-adjacent), then shfl re-fragmentation
        auto PK = [](float a, float b) -> int {
            unsigned short ua = __builtin_bit_cast(unsigned short, (bf16)a);
            unsigned short ub = __builtin_bit_cast(unsigned short, (bf16)b);
            return (int)((unsigned)ua | ((unsigned)ub << 16));
        };
        int c0 = PK(x[0], x[1]),  c1 = PK(x[2], x[3]);
        int c2 = PK(x[4], x[5]),  c3 = PK(x[6], x[7]);
        int c4 = PK(x[8], x[9]),  c5 = PK(x[10], x[11]);
        int c6 = PK(x[12], x[13]), c7 = PK(x[14], x[15]);

        unsigned a00 = (unsigned)__shfl(c0, src0), a01 = (unsigned)__shfl(c2, src0);
        unsigned a10 = (unsigned)__shfl(c1, src0), a11 = (unsigned)__shfl(c3, src0);
        unsigned a20 = (unsigned)__shfl(c0, src1), a21 = (unsigned)__shfl(c2, src1);
        unsigned a30 = (unsigned)__shfl(c1, src1), a31 = (unsigned)__shfl(c3, src1);
        unsigned b00 = (unsigned)__shfl(c4, src0), b01 = (unsigned)__shfl(c6, src0);
        unsigned b10 = (unsigned)__shfl(c5, src0), b11 = (unsigned)__shfl(c7, src0);
        unsigned b20 = (unsigned)__shfl(c4, src1), b21 = (unsigned)__shfl(c6, src1);
        unsigned b30 = (unsigned)__shfl(c5, src1), b31 = (unsigned)__shfl(c7, src1);
        uint4v u0 = { hi ? a01 : a00, hi ? a11 : a10, hi ? a21 : a20, hi ? a31 : a30 };
        uint4v u1 = { hi ? b01 : b00, hi ? b11 : b10, hi ? b21 : b20, hi ? b31 : b30 };
        bf16x8 pb0 = __builtin_bit_cast(bf16x8, u0);
        bf16x8 pb1 = __builtin_bit_cast(bf16x8, u1);

        o0 = __builtin_amdgcn_mfma_f32_16x16x32_bf16(va00, pb0, o0, 0, 0, 0);
        o0 = __builtin_amdgcn_mfma_f32_16x16x32_bf16(va01, pb1, o0, 0, 0, 0);
        o1 = __builtin_amdgcn_mfma_f32_16x16x32_bf16(va10, pb0, o1, 0, 0, 0);
        o1 = __builtin_amdgcn_mfma_f32_16x16x32_bf16(va11, pb1, o1, 0, 0, 0);
    }
    int hq = h * SN + q0 + qi;
    *(f32x4*)(po + (hq * KCHT + c) * DK + 4 * g)      = o0;
    *(f32x4*)(po + (hq * KCHT + c) * DK + 16 + 4 * g) = o1;
    if (g == 0) { pm[hq * KCHT + c] = m; pl[hq * KCHT + c] = lsum; }
}

// ---------------------------------------------------------------------------
// Kernel 4: split-K combine. One thread per (h, q, d).
// ---------------------------------------------------------------------------
template<int KCHT>
__global__ void __launch_bounds__(256) combine_kernel(
    const float* __restrict__ po, const float* __restrict__ pm,
    const float* __restrict__ pl, bf16* __restrict__ aout)
{
    int idx = blockIdx.x * 256 + threadIdx.x;
    int d = idx & (DK - 1), hq = idx >> 5;
    int h = hq >> 11, qr = hq & (SN - 1);
    float mv[KCHT], lv[KCHT];
    #pragma unroll
    for (int c = 0; c < KCHT; c++) { mv[c] = pm[hq * KCHT + c]; lv[c] = pl[hq * KCHT + c]; }
    float M = mv[0];
    #pragma unroll
    for (int c = 1; c < KCHT; c++) M = fmaxf(M, mv[c]);
    float L = 0.f, o = 0.f;
    const float* p = po + hq * KCHT * DK + d;
    #pragma unroll
    for (int c = 0; c < KCHT; c++) {
        float w = __expf(mv[c] - M);
        L += w * lv[c];
        o += w * p[c * DK];
    }
    aout[qr * HD + h * DK + d] = (bf16)(o / L);
}

// ---------------------------------------------------------------------------
extern "C" void kernel_launch(void* const* d_in, const int* in_sizes, int n_in,
                              void* d_out, int out_size, void* d_ws, size_t ws_size,
                              hipStream_t stream)
{
    static const int expect[22] = {
        SN * SN, SN * SN, SN * SN,
        SN * HD, SN * HD, SN * HD,
        HD * HD, HD, HD * HD, HD,
        HD * HD, HD, HD * HD, HD,
        2 * BH, BH, BH, 1,
        2 * BH, BH, BH, 1
    };
    if (n_in != 22) return;
    for (int i = 0; i < 22; i++) if (in_sizes[i] != expect[i]) return;

    const int*   label   = (const int*)  d_in[0];
    const float* dist    = (const float*)d_in[1];
    const float* contact = (const float*)d_in[2];
    const float* q  = (const float*)d_in[3];
    const float* k  = (const float*)d_in[4];
    const float* v  = (const float*)d_in[5];
    const float* Wq = (const float*)d_in[6];  const float* bq = (const float*)d_in[7];
    const float* Wk = (const float*)d_in[8];  const float* bk = (const float*)d_in[9];
    const float* Wv = (const float*)d_in[10]; const float* bv = (const float*)d_in[11];
    const float* Wo = (const float*)d_in[12]; const float* bo = (const float*)d_in[13];
    const float* Wd1 = (const float*)d_in[14]; const float* bd1 = (const float*)d_in[15];
    const float* Wd2 = (const float*)d_in[16]; const float* bd2 = (const float*)d_in[17];
    const float* Wc1 = (const float*)d_in[18]; const float* bc1 = (const float*)d_in[19];
    const float* Wc2 = (const float*)d_in[20]; const float* bc2 = (const float*)d_in[21];

    char* ws = (char*)d_ws;
    bf16*  qh   = (bf16*)(ws);                  // 1 MB projected Q [N][256]
    bf16*  kh   = (bf16*)(ws + (1u << 20));     // 1 MB projected K [N][256]
    bf16*  vt   = (bf16*)(ws + (2u << 20));     // 1 MB projected V transposed
    bf16*  aout = (bf16*)(ws + (3u << 20));     // 1 MB attention output
    bf16*  wt   = (bf16*)(ws + (4u << 20));     // 512 KB transposed weights x4
    float* po   = (float*)(ws + (5u << 20));

    prep_wt_kernel<<<dim3(32), 256, 0, stream>>>(Wq, Wk, Wv, Wo, wt);
    qkv_kernel<<<dim3(256, 3), 256, 0, stream>>>(q, k, v, wt, bq, bk, bv, qh, kh, vt);

    // split-K depth: KCH=8 needs 5MB + 16MB po + 2x512KB = 22MB of ws.
    size_t need8 = (5u << 20) + (size_t)NHEAD * SN * 8 * DK * 4 + 2u * NHEAD * SN * 8 * 4;
    if (ws_size >= need8 + (1u << 20)) {
        float* pm = (float*)(ws + (5u << 20) + (size_t)NHEAD * SN * 8 * DK * 4);
        float* pl = pm + NHEAD * SN * 8;
        attn_kernel<8><<<dim3(NHEAD * 64 * 8), 128, 0, stream>>>(
            qh, kh, vt, label, dist, contact,
            Wd1, bd1, Wd2, bd2, Wc1, bc1, Wc2, bc2, po, pm, pl);
        combine_kernel<8><<<dim3(NHEAD * SN * DK / 256), 256, 0, stream>>>(po, pm, pl, aout);
    } else {
        float* pm = (float*)(ws + (13u << 20));
        float* pl = pm + NHEAD * SN * 4;
        attn_kernel<4><<<dim3(NHEAD * 64 * 4), 128, 0, stream>>>(
            qh, kh, vt, label, dist, contact,
            Wd1, bd1, Wd2, bd2, Wc1, bc1, Wc2, bc2, po, pm, pl);
        combine_kernel<4><<<dim3(NHEAD * SN * DK / 256), 256, 0, stream>>>(po, pm, pl, aout);
    }

    oproj_kernel<<<dim3(256), 256, 0, stream>>>(aout, wt + 3 * HD * HD, bo, (float*)d_out);
}

// Round 12
// 199.746 us; speedup vs baseline: 1.1147x; 1.1147x over previous
//
#include <hip/hip_runtime.h>
#include <hip/hip_bf16.h>

#define SN 2048      // sequence length
#define HD 256       // hidden
#define NHEAD 8
#define DK 32
#define BH 16

typedef __bf16 bf16;
typedef __bf16 bf16x8 __attribute__((ext_vector_type(8)));
typedef __bf16 bf16x4 __attribute__((ext_vector_type(4)));
typedef float f32x4 __attribute__((ext_vector_type(4)));
typedef int i32x4 __attribute__((ext_vector_type(4)));
typedef unsigned uint4v __attribute__((ext_vector_type(4)));

// ---------------------------------------------------------------------------
// Kernel 1 (fused prep): blocks 0..31 transpose Wq/Wk/Wv/Wo (fp32->bf16,
// [k][n]->[n][k]); blocks 32.. evaluate the bias plane:
//   bias(q,k) = ad*dist + ac*contact + bl*label + dl   (affine MLP fold)
// stored fp32 [N][N]. Streaming, HBM-bound, latency-immune — this hoists
// 12 loads + ~110 VALU per tile out of every attention wave (R11 lesson:
// attn is serial-latency-bound; bias eval was the biggest chain segment).
// ---------------------------------------------------------------------------
__global__ void __launch_bounds__(256) prep_kernel(
    const float* __restrict__ Wq, const float* __restrict__ Wk,
    const float* __restrict__ Wv, const float* __restrict__ Wo,
    const int* __restrict__ label, const float* __restrict__ dist,
    const float* __restrict__ contact,
    const float* __restrict__ Wd1, const float* __restrict__ bd1,
    const float* __restrict__ Wd2, const float* __restrict__ bd2,
    const float* __restrict__ Wc1, const float* __restrict__ bc1,
    const float* __restrict__ Wc2, const float* __restrict__ bc2,
    bf16* __restrict__ wt, float* __restrict__ plane)
{
    int bid = blockIdx.x;
    int t = threadIdx.x;
    if (bid < 32) {
        __shared__ bf16 tile[32][HD + 8];
        int mat = bid >> 3, rc = bid & 7;
        const float* W = mat == 0 ? Wq : mat == 1 ? Wk : mat == 2 ? Wv : Wo;
        bf16* Wt = wt + mat * HD * HD;
        int r0 = rc * 32;
        #pragma unroll
        for (int i = 0; i < 32; i++) tile[i][t] = (bf16)W[(r0 + i) * HD + t];
        __syncthreads();
        #pragma unroll
        for (int i = 0; i < 32; i++) Wt[t * HD + r0 + i] = tile[i][t];
        return;
    }
    // fold the two affine pair-MLPs into 4 scalars (wave-uniform, fp32)
    float ad = 0.f, bld = 0.f, dd = bd2[0];
    #pragma unroll
    for (int j = 0; j < BH; j++) {
        float w2 = Wd2[j];
        ad  += Wd1[j] * w2;
        bld += Wd1[BH + j] * w2;
        dd  += bd1[j] * w2;
    }
    float ac = 0.f, blc = 0.f, dc = bc2[0];
    #pragma unroll
    for (int j = 0; j < BH; j++) {
        float w2 = Wc2[j];
        ac  += Wc1[j] * w2;
        blc += Wc1[BH + j] * w2;
        dc  += bc1[j] * w2;
    }
    float bl = bld + blc, dl = dd + dc;

    int base = (bid - 32) * 2048 + t * 8;
    f32x4 d0 = *(const f32x4*)(dist + base),    d1 = *(const f32x4*)(dist + base + 4);
    f32x4 c0 = *(const f32x4*)(contact + base), c1 = *(const f32x4*)(contact + base + 4);
    i32x4 l0 = *(const i32x4*)(label + base),   l1 = *(const i32x4*)(label + base + 4);
    f32x4 o0, o1;
    #pragma unroll
    for (int e = 0; e < 4; e++) {
        o0[e] = ad * d0[e] + ac * c0[e] + bl * (float)l0[e] + dl;
        o1[e] = ad * d1[e] + ac * c1[e] + bl * (float)l1[e] + dl;
    }
    *(f32x4*)(plane + base)     = o0;
    *(f32x4*)(plane + base + 4) = o1;
}

// ---------------------------------------------------------------------------
// 2048x256 @ 256x256 GEMM (MFMA 16x16x32 bf16), Wt [n][k], 2-deep register
// rotation. AF32: fp32 A. MODE 0: out[m][n]; MODE 1: out[n][m]. OUTF32: fp32.
// ---------------------------------------------------------------------------
template<bool AF32, int MODE, bool OUTF32>
__device__ __forceinline__ void gemm_body(
    const void* __restrict__ Ap, const bf16* __restrict__ Wt,
    const float* __restrict__ bias, void* __restrict__ outp, int bid)
{
    int wave = threadIdx.x >> 6, lane = threadIdx.x & 63;
    int g = lane >> 4, qi = lane & 15;
    int mblk = bid & 31, nblk = bid >> 5;
    int m0 = mblk * 64 + wave * 16, n0 = nblk * 32;
    f32x4 acc0 = {0.f, 0.f, 0.f, 0.f}, acc1 = {0.f, 0.f, 0.f, 0.f};
    const bf16* W0 = Wt + (n0 + qi) * HD + 8 * g;
    const bf16* W1 = W0 + 16 * HD;

    auto loadA = [&](int ks) -> bf16x8 {
        if constexpr (AF32) {
            const float* Ar = (const float*)Ap + (m0 + qi) * HD + 8 * g + ks * 32;
            f32x4 lo = *(const f32x4*)Ar;
            f32x4 hi = *(const f32x4*)(Ar + 4);
            bf16x8 a;
            #pragma unroll
            for (int e = 0; e < 4; e++) { a[e] = (bf16)lo[e]; a[4 + e] = (bf16)hi[e]; }
            return a;
        } else {
            return *(const bf16x8*)((const bf16*)Ap + (m0 + qi) * HD + 8 * g + ks * 32);
        }
    };

    bf16x8 a_c  = loadA(0);
    bf16x8 b0_c = *(const bf16x8*)(W0);
    bf16x8 b1_c = *(const bf16x8*)(W1);
    #pragma unroll
    for (int ks = 0; ks < 8; ks++) {
        bf16x8 a_n, b0_n, b1_n;
        if (ks < 7) {
            a_n  = loadA(ks + 1);
            b0_n = *(const bf16x8*)(W0 + (ks + 1) * 32);
            b1_n = *(const bf16x8*)(W1 + (ks + 1) * 32);
        }
        acc0 = __builtin_amdgcn_mfma_f32_16x16x32_bf16(a_c, b0_c, acc0, 0, 0, 0);
        acc1 = __builtin_amdgcn_mfma_f32_16x16x32_bf16(a_c, b1_c, acc1, 0, 0, 0);
        if (ks < 7) { a_c = a_n; b0_c = b0_n; b1_c = b1_n; }
    }
    float bv0 = bias[n0 + qi], bv1 = bias[n0 + 16 + qi];
    if constexpr (MODE == 0) {
        if constexpr (OUTF32) {
            float* out = (float*)outp;
            #pragma unroll
            for (int r = 0; r < 4; r++) {
                int m = m0 + 4 * g + r;
                out[m * HD + n0 + qi]      = acc0[r] + bv0;
                out[m * HD + n0 + 16 + qi] = acc1[r] + bv1;
            }
        } else {
            bf16* out = (bf16*)outp;
            #pragma unroll
            for (int r = 0; r < 4; r++) {
                int m = m0 + 4 * g + r;
                out[m * HD + n0 + qi]      = (bf16)(acc0[r] + bv0);
                out[m * HD + n0 + 16 + qi] = (bf16)(acc1[r] + bv1);
            }
        }
    } else {
        bf16* out = (bf16*)outp;
        bf16x4 v0, v1;
        #pragma unroll
        for (int r = 0; r < 4; r++) { v0[r] = (bf16)(acc0[r] + bv0); v1[r] = (bf16)(acc1[r] + bv1); }
        *(bf16x4*)(out + (n0 + qi) * SN + m0 + 4 * g)      = v0;
        *(bf16x4*)(out + (n0 + 16 + qi) * SN + m0 + 4 * g) = v1;
    }
}

__global__ void __launch_bounds__(256) qkv_kernel(
    const float* __restrict__ q, const float* __restrict__ k, const float* __restrict__ v,
    const bf16* __restrict__ wt,
    const float* __restrict__ bq, const float* __restrict__ bk, const float* __restrict__ bv,
    bf16* __restrict__ qh, bf16* __restrict__ kh, bf16* __restrict__ vt)
{
    int w = blockIdx.y;
    if (w == 0)      gemm_body<true, 0, false>(q, wt,               bq, qh, blockIdx.x);
    else if (w == 1) gemm_body<true, 0, false>(k, wt + HD * HD,     bk, kh, blockIdx.x);
    else             gemm_body<true, 1, false>(v, wt + 2 * HD * HD, bv, vt, blockIdx.x);
}

__global__ void __launch_bounds__(256) oproj_kernel(
    const bf16* __restrict__ A, const bf16* __restrict__ wt3,
    const float* __restrict__ bo, float* __restrict__ out)
{
    gemm_body<false, 0, true>(A, wt3, bo, out, blockIdx.x);
}

// ---------------------------------------------------------------------------
// Kernel 3: MFMA flash attention, split-K, fence-free shfl P-exchange.
// PLANE=true: bias read as one f32x4 per 16-key sub-block from the
// precomputed plane (4 loads/tile instead of 12 + no per-wave MLP fold).
// ---------------------------------------------------------------------------
template<int KCHT, bool PLANE>
__global__ void __launch_bounds__(128) attn_kernel(
    const bf16* __restrict__ qh, const bf16* __restrict__ kh,
    const bf16* __restrict__ vt, const float* __restrict__ plane,
    const int* __restrict__ label, const float* __restrict__ dist,
    const float* __restrict__ contact,
    const float* __restrict__ Wd1, const float* __restrict__ bd1,
    const float* __restrict__ Wd2, const float* __restrict__ bd2,
    const float* __restrict__ Wc1, const float* __restrict__ bc1,
    const float* __restrict__ Wc2, const float* __restrict__ bc2,
    float* __restrict__ po, float* __restrict__ pm, float* __restrict__ pl)
{
    constexpr int KT = SN / KCHT / 64;   // 64-key tiles per chunk
    int wave = threadIdx.x >> 6, lane = threadIdx.x & 63;
    int g = lane >> 4, qi = lane & 15;
    int h = blockIdx.x / (64 * KCHT);
    int rem = blockIdx.x % (64 * KCHT);
    int qb = rem / KCHT, c = rem % KCHT;
    int q0 = qb * 32 + wave * 16;
    int kbase = c * (KT * 64);

    float ad = 0.f, bl = 0.f, acoef = 0.f, dl = 0.f;
    if constexpr (!PLANE) {
        float bld = 0.f, dd = bd2[0];
        #pragma unroll
        for (int j = 0; j < BH; j++) {
            float w2 = Wd2[j];
            ad  += Wd1[j] * w2;
            bld += Wd1[BH + j] * w2;
            dd  += bd1[j] * w2;
        }
        float blc = 0.f, dc = bc2[0];
        #pragma unroll
        for (int j = 0; j < BH; j++) {
            float w2 = Wc2[j];
            acoef += Wc1[j] * w2;
            blc   += Wc1[BH + j] * w2;
            dc    += bc1[j] * w2;
        }
        bl = bld + blc; dl = dd + dc;
    }

    bf16x8 qf = *(const bf16x8*)(qh + (q0 + qi) * HD + h * DK + 8 * g);
    const bf16* kp  = kh + h * DK + 8 * g + kbase * HD;
    const bf16* v0p = vt + (h * DK + qi) * SN + 8 * g + kbase;
    const bf16* v1p = v0p + 16 * SN;
    const float* bp = plane   + (q0 + qi) * SN + 4 * g + kbase;
    const float* dp = dist    + (q0 + qi) * SN + 4 * g + kbase;
    const float* cp = contact + (q0 + qi) * SN + 4 * g + kbase;
    const int*   lp = label   + (q0 + qi) * SN + 4 * g + kbase;

    const float scale = 0.17677669529663687f;  // 32^-0.5
    float m = -1e30f, lsum = 0.f;
    f32x4 o0 = {0.f, 0.f, 0.f, 0.f}, o1 = {0.f, 0.f, 0.f, 0.f};

    int src0 = ((lane >> 4) & 1) * 32 + (lane & 15);
    int src1 = src0 + 16;
    bool hi = lane >= 32;

    #pragma unroll
    for (int kt = 0; kt < KT; kt++) {
        int key0 = kt * 64;
        bf16x8 kf0 = *(const bf16x8*)(kp + (key0 +  0 + qi) * HD);
        bf16x8 kf1 = *(const bf16x8*)(kp + (key0 + 16 + qi) * HD);
        bf16x8 kf2 = *(const bf16x8*)(kp + (key0 + 32 + qi) * HD);
        bf16x8 kf3 = *(const bf16x8*)(kp + (key0 + 48 + qi) * HD);
        f32x4 bv[4];
        if constexpr (PLANE) {
            #pragma unroll
            for (int s = 0; s < 4; s++) bv[s] = *(const f32x4*)(bp + key0 + 16 * s);
        } else {
            #pragma unroll
            for (int s = 0; s < 4; s++) {
                f32x4 dv = *(const f32x4*)(dp + key0 + 16 * s);
                f32x4 cv = *(const f32x4*)(cp + key0 + 16 * s);
                i32x4 lv = *(const i32x4*)(lp + key0 + 16 * s);
                #pragma unroll
                for (int r = 0; r < 4; r++)
                    bv[s][r] = ad * dv[r] + acoef * cv[r] + bl * (float)lv[r] + dl;
            }
        }
        bf16x8 va00 = *(const bf16x8*)(v0p + key0);
        bf16x8 va01 = *(const bf16x8*)(v0p + key0 + 32);
        bf16x8 va10 = *(const bf16x8*)(v1p + key0);
        bf16x8 va11 = *(const bf16x8*)(v1p + key0 + 32);

        f32x4 zero = {0.f, 0.f, 0.f, 0.f};
        f32x4 s0 = __builtin_amdgcn_mfma_f32_16x16x32_bf16(kf0, qf, zero, 0, 0, 0);
        f32x4 s1 = __builtin_amdgcn_mfma_f32_16x16x32_bf16(kf1, qf, zero, 0, 0, 0);
        f32x4 s2 = __builtin_amdgcn_mfma_f32_16x16x32_bf16(kf2, qf, zero, 0, 0, 0);
        f32x4 s3 = __builtin_amdgcn_mfma_f32_16x16x32_bf16(kf3, qf, zero, 0, 0, 0);
        float x[16];
        #pragma unroll
        for (int r = 0; r < 4; r++) {
            x[r]      = s0[r] * scale + bv[0][r];
            x[4 + r]  = s1[r] * scale + bv[1][r];
            x[8 + r]  = s2[r] * scale + bv[2][r];
            x[12 + r] = s3[r] * scale + bv[3][r];
        }
        float t0 = fmaxf(x[0], x[1]),   t1 = fmaxf(x[2], x[3]);
        float t2 = fmaxf(x[4], x[5]),   t3 = fmaxf(x[6], x[7]);
        float t4 = fmaxf(x[8], x[9]),   t5 = fmaxf(x[10], x[11]);
        float t6 = fmaxf(x[12], x[13]), t7 = fmaxf(x[14], x[15]);
        float tm = fmaxf(fmaxf(fmaxf(t0, t1), fmaxf(t2, t3)),
                         fmaxf(fmaxf(t4, t5), fmaxf(t6, t7)));
        tm = fmaxf(tm, __shfl_xor(tm, 16));
        tm = fmaxf(tm, __shfl_xor(tm, 32));
        float mnew = fmaxf(m, tm);
        float f = __expf(m - mnew);
        float ps = 0.f;
        #pragma unroll
        for (int i = 0; i < 16; i++) { x[i] = __expf(x[i] - mnew); ps += x[i]; }
        ps += __shfl_xor(ps, 16);
        ps += __shfl_xor(ps, 32);
        lsum = lsum * f + ps;
        m = mnew;
        #pragma unroll
        for (int r = 0; r < 4; r++) { o0[r] *= f; o1[r] *= f; }

        // pack P to bf16 key-adjacent pairs, shfl re-fragmentation (fence-free)
        auto PK = [](float a, float b) -> int {
            unsigned short ua = __builtin_bit_cast(unsigned short, (bf16)a);
            unsigned short ub = __builtin_bit_cast(unsigned short, (bf16)b);
            return (int)((unsigned)ua | ((unsigned)ub << 16));
        };
        int c0 = PK(x[0], x[1]),   c1 = PK(x[2], x[3]);
        int c2 = PK(x[4], x[5]),   c3 = PK(x[6], x[7]);
        int c4 = PK(x[8], x[9]),   c5 = PK(x[10], x[11]);
        int c6 = PK(x[12], x[13]), c7 = PK(x[14], x[15]);

        unsigned a00 = (unsigned)__shfl(c0, src0), a01 = (unsigned)__shfl(c2, src0);
        unsigned a10 = (unsigned)__shfl(c1, src0), a11 = (unsigned)__shfl(c3, src0);
        unsigned a20 = (unsigned)__shfl(c0, src1), a21 = (unsigned)__shfl(c2, src1);
        unsigned a30 = (unsigned)__shfl(c1, src1), a31 = (unsigned)__shfl(c3, src1);
        unsigned b00 = (unsigned)__shfl(c4, src0), b01 = (unsigned)__shfl(c6, src0);
        unsigned b10 = (unsigned)__shfl(c5, src0), b11 = (unsigned)__shfl(c7, src0);
        unsigned b20 = (unsigned)__shfl(c4, src1), b21 = (unsigned)__shfl(c6, src1);
        unsigned b30 = (unsigned)__shfl(c5, src1), b31 = (unsigned)__shfl(c7, src1);
        uint4v u0 = { hi ? a01 : a00, hi ? a11 : a10, hi ? a21 : a20, hi ? a31 : a30 };
        uint4v u1 = { hi ? b01 : b00, hi ? b11 : b10, hi ? b21 : b20, hi ? b31 : b30 };
        bf16x8 pb0 = __builtin_bit_cast(bf16x8, u0);
        bf16x8 pb1 = __builtin_bit_cast(bf16x8, u1);

        o0 = __builtin_amdgcn_mfma_f32_16x16x32_bf16(va00, pb0, o0, 0, 0, 0);
        o0 = __builtin_amdgcn_mfma_f32_16x16x32_bf16(va01, pb1, o0, 0, 0, 0);
        o1 = __builtin_amdgcn_mfma_f32_16x16x32_bf16(va10, pb0, o1, 0, 0, 0);
        o1 = __builtin_amdgcn_mfma_f32_16x16x32_bf16(va11, pb1, o1, 0, 0, 0);
    }
    int hq = h * SN + q0 + qi;
    *(f32x4*)(po + (hq * KCHT + c) * DK + 4 * g)      = o0;
    *(f32x4*)(po + (hq * KCHT + c) * DK + 16 + 4 * g) = o1;
    if (g == 0) { pm[hq * KCHT + c] = m; pl[hq * KCHT + c] = lsum; }
}

// ---------------------------------------------------------------------------
// Kernel 4: split-K combine. One thread per (h, q, d).
// ---------------------------------------------------------------------------
template<int KCHT>
__global__ void __launch_bounds__(256) combine_kernel(
    const float* __restrict__ po, const float* __restrict__ pm,
    const float* __restrict__ pl, bf16* __restrict__ aout)
{
    int idx = blockIdx.x * 256 + threadIdx.x;
    int d = idx & (DK - 1), hq = idx >> 5;
    int h = hq >> 11, qr = hq & (SN - 1);
    float mv[KCHT], lv[KCHT];
    #pragma unroll
    for (int c = 0; c < KCHT; c++) { mv[c] = pm[hq * KCHT + c]; lv[c] = pl[hq * KCHT + c]; }
    float M = mv[0];
    #pragma unroll
    for (int c = 1; c < KCHT; c++) M = fmaxf(M, mv[c]);
    float L = 0.f, o = 0.f;
    const float* p = po + hq * KCHT * DK + d;
    #pragma unroll
    for (int c = 0; c < KCHT; c++) {
        float w = __expf(mv[c] - M);
        L += w * lv[c];
        o += w * p[c * DK];
    }
    aout[qr * HD + h * DK + d] = (bf16)(o / L);
}

// ---------------------------------------------------------------------------
extern "C" void kernel_launch(void* const* d_in, const int* in_sizes, int n_in,
                              void* d_out, int out_size, void* d_ws, size_t ws_size,
                              hipStream_t stream)
{
    static const int expect[22] = {
        SN * SN, SN * SN, SN * SN,
        SN * HD, SN * HD, SN * HD,
        HD * HD, HD, HD * HD, HD,
        HD * HD, HD, HD * HD, HD,
        2 * BH, BH, BH, 1,
        2 * BH, BH, BH, 1
    };
    if (n_in != 22) return;
    for (int i = 0; i < 22; i++) if (in_sizes[i] != expect[i]) return;

    const int*   label   = (const int*)  d_in[0];
    const float* dist    = (const float*)d_in[1];
    const float* contact = (const float*)d_in[2];
    const float* q  = (const float*)d_in[3];
    const float* k  = (const float*)d_in[4];
    const float* v  = (const float*)d_in[5];
    const float* Wq = (const float*)d_in[6];  const float* bq = (const float*)d_in[7];
    const float* Wk = (const float*)d_in[8];  const float* bk = (const float*)d_in[9];
    const float* Wv = (const float*)d_in[10]; const float* bv = (const float*)d_in[11];
    const float* Wo = (const float*)d_in[12]; const float* bo = (const float*)d_in[13];
    const float* Wd1 = (const float*)d_in[14]; const float* bd1 = (const float*)d_in[15];
    const float* Wd2 = (const float*)d_in[16]; const float* bd2 = (const float*)d_in[17];
    const float* Wc1 = (const float*)d_in[18]; const float* bc1 = (const float*)d_in[19];
    const float* Wc2 = (const float*)d_in[20]; const float* bc2 = (const float*)d_in[21];

    const size_t MB = 1u << 20;
    char* ws = (char*)d_ws;
    bf16*  qh    = (bf16*)(ws);                  // 1 MB projected Q [N][256]
    bf16*  kh    = (bf16*)(ws + 1 * MB);         // 1 MB projected K [N][256]
    bf16*  vt    = (bf16*)(ws + 2 * MB);         // 1 MB projected V transposed
    bf16*  aout  = (bf16*)(ws + 3 * MB);         // 1 MB attention output
    bf16*  wt    = (bf16*)(ws + 4 * MB);         // 512 KB transposed weights x4
    float* plane = (float*)(ws + 5 * MB);        // 16 MB fp32 bias plane

    prep_kernel<<<dim3(32 + SN * SN / 2048), 256, 0, stream>>>(
        Wq, Wk, Wv, Wo, label, dist, contact,
        Wd1, bd1, Wd2, bd2, Wc1, bc1, Wc2, bc2, wt, plane);

    qkv_kernel<<<dim3(256, 3), 256, 0, stream>>>(q, k, v, wt, bq, bk, bv, qh, kh, vt);

    if (ws_size >= 38 * MB) {
        // plane + KCH=8: po 16 MB @21MB, pm/pl @37MB
        float* po = (float*)(ws + 21 * MB);
        float* pm = (float*)(ws + 37 * MB);
        float* pl = pm + NHEAD * SN * 8;
        attn_kernel<8, true><<<dim3(NHEAD * 64 * 8), 128, 0, stream>>>(
            qh, kh, vt, plane, label, dist, contact,
            Wd1, bd1, Wd2, bd2, Wc1, bc1, Wc2, bc2, po, pm, pl);
        combine_kernel<8><<<dim3(NHEAD * SN * DK / 256), 256, 0, stream>>>(po, pm, pl, aout);
    } else if (ws_size >= 30 * MB) {
        // plane + KCH=4: po 8 MB @21MB, pm/pl @29MB
        float* po = (float*)(ws + 21 * MB);
        float* pm = (float*)(ws + 29 * MB);
        float* pl = pm + NHEAD * SN * 4;
        attn_kernel<4, true><<<dim3(NHEAD * 64 * 4), 128, 0, stream>>>(
            qh, kh, vt, plane, label, dist, contact,
            Wd1, bd1, Wd2, bd2, Wc1, bc1, Wc2, bc2, po, pm, pl);
        combine_kernel<4><<<dim3(NHEAD * SN * DK / 256), 256, 0, stream>>>(po, pm, pl, aout);
    } else {
        // proven R11 path: on-the-fly bias, KCH=8, po 16 MB @5MB (overwrites plane)
        float* po = (float*)(ws + 5 * MB);
        float* pm = (float*)(ws + 21 * MB);
        float* pl = pm + NHEAD * SN * 8;
        attn_kernel<8, false><<<dim3(NHEAD * 64 * 8), 128, 0, stream>>>(
            qh, kh, vt, plane, label, dist, contact,
            Wd1, bd1, Wd2, bd2, Wc1, bc1, Wc2, bc2, po, pm, pl);
        combine_kernel<8><<<dim3(NHEAD * SN * DK / 256), 256, 0, stream>>>(po, pm, pl, aout);
    }

    oproj_kernel<<<dim3(256), 256, 0, stream>>>(aout, wt + 3 * HD * HD, bo, (float*)d_out);
}